// Round 4
// baseline (4016.805 us; speedup 1.0000x reference)
//
#include <hip/hip_runtime.h>
#include <hip/hip_fp16.h>

// LSTM: B=64, T=2048, D=128, U=256.
// Phase 1: xz = inputs @ Wx (f32 tiled GEMM) -- R1/R3-proven, unchanged.
// Phase 2: one WG per batch, 1024 threads, ONE column per thread.
//          Wh col j: 92 k-pairs in VGPRs (fits 128-VGPR budget at 4 waves/SIMD)
//          + 36 k-pairs in LDS as f16x8 (144KB, b128 reads).
//          R1 counters showed VGPR_Count=128 < 192 needed at 2 cols/thread ->
//          weights reloaded from scratch/L1 every step (L1-BW-bound, VALU 16%).

#define NB 64
#define NT 2048
#define ND 128
#define NU 256
#define N4U 1024

#define WREG 92   // k-pairs per column in VGPRs (pairs 0..91)
#define WLG 9     // LDS f16x8 groups (pairs 92..127, 4 pairs per group)

typedef _Float16 f16;
typedef _Float16 f16x2 __attribute__((ext_vector_type(2)));
typedef _Float16 f16x8 __attribute__((ext_vector_type(8)));
typedef float f32x4 __attribute__((ext_vector_type(4)));

__device__ __forceinline__ float dot2(f16x2 a, f16x2 b, float c) {
  return __builtin_amdgcn_fdot2(a, b, c, false);
}

__device__ __forceinline__ float sigm(float x) { return 1.0f / (1.0f + __expf(-x)); }
__device__ __forceinline__ float tanh_(float x) { return 1.0f - 2.0f / (__expf(2.0f * x) + 1.0f); }

// ---------------- Phase 1: xz[b][t - t0][j] = sum_k X[b][t][k] * Wx[k][j] ----
// grid: (tc/64, B, 16), block 256. Tile: 64 rows (t) x 64 cols, K=128 in LDS.
__global__ __launch_bounds__(256) void xz_gemm(const float* __restrict__ X,
                                               const float* __restrict__ Wx,
                                               float* __restrict__ XZ,
                                               int t0, int tc) {
  __shared__ __align__(16) float xs[64][ND];   // [row][k] 32KB
  __shared__ __align__(16) float ws[ND][64];   // [k][col] 32KB
  const int tid = threadIdx.x;
  const int b = blockIdx.y;
  const int row0 = t0 + blockIdx.x * 64;
  const int col0 = blockIdx.z * 64;

  {
    const float* src = X + ((size_t)b * NT + row0) * ND;
#pragma unroll
    for (int ii = 0; ii < 8; ++ii) {
      int q = tid + 256 * ii;          // 0..2047 float4s
      int r = q >> 5;                  // 32 float4 per row
      int k4 = q & 31;
      f32x4 v = *(const f32x4*)(src + (size_t)r * ND + 4 * k4);
      *(f32x4*)&xs[r][4 * k4] = v;
    }
#pragma unroll
    for (int ii = 0; ii < 8; ++ii) {
      int q = tid + 256 * ii;
      int k = q >> 4;                  // 16 float4 per k-row
      int c4 = q & 15;
      f32x4 v = *(const f32x4*)(Wx + (size_t)k * N4U + col0 + 4 * c4);
      *(f32x4*)&ws[k][4 * c4] = v;
    }
  }
  __syncthreads();

  const int tx = tid & 15, ty = tid >> 4;
  float acc[4][4];
#pragma unroll
  for (int i = 0; i < 4; ++i)
#pragma unroll
    for (int j = 0; j < 4; ++j) acc[i][j] = 0.0f;

#pragma unroll 8
  for (int k = 0; k < ND; ++k) {
    f32x4 bv = *(const f32x4*)&ws[k][4 * tx];
    float a0 = xs[4 * ty + 0][k];
    float a1 = xs[4 * ty + 1][k];
    float a2 = xs[4 * ty + 2][k];
    float a3 = xs[4 * ty + 3][k];
#pragma unroll
    for (int j = 0; j < 4; ++j) {
      acc[0][j] += a0 * bv[j];
      acc[1][j] += a1 * bv[j];
      acc[2][j] += a2 * bv[j];
      acc[3][j] += a3 * bv[j];
    }
  }

  float* dst = XZ + ((size_t)b * tc + (row0 - t0)) * N4U + col0;
#pragma unroll
  for (int i = 0; i < 4; ++i) {
    f32x4 v;
#pragma unroll
    for (int j = 0; j < 4; ++j) v[j] = acc[i][j];
    *(f32x4*)(dst + (size_t)(4 * ty + i) * N4U + 4 * tx) = v;
  }
}

// ---------------- Phase 2: sequential scan, one WG per batch ----------------
// block 1024: thread t owns output column j = t.
__global__ __launch_bounds__(1024, 4) void lstm_seq(const float* __restrict__ Wh,
                                                    const float* __restrict__ bias,
                                                    const float* __restrict__ XZ,
                                                    float* __restrict__ out,
                                                    float* __restrict__ state,
                                                    int t0, int tc) {
  extern __shared__ f16x8 wl[];                 // [WLG][1024] f16x8 = 144KB
  __shared__ float zbuf[N4U];                   // 4KB
  __shared__ __align__(16) f16 hbuf[NU];        // 512B

  const int t = threadIdx.x;
  const int b = blockIdx.x;

  const float bj = bias[t];

  // Wh column t as f16 pairs: pairs 0..91 -> VGPRs, pairs 92..127 -> LDS f16x8.
  f16x2 wr[WREG];
#pragma unroll
  for (int p = 0; p < WREG; ++p) {
    f16x2 w;
    w.x = (f16)Wh[(size_t)(2 * p) * N4U + t];
    w.y = (f16)Wh[(size_t)(2 * p + 1) * N4U + t];
    wr[p] = w;
  }
#pragma unroll
  for (int g = 0; g < WLG; ++g) {
    f16x8 w;
#pragma unroll
    for (int q = 0; q < 4; ++q) {
      int p = WREG + 4 * g + q;
      w[2 * q]     = (f16)Wh[(size_t)(2 * p) * N4U + t];
      w[2 * q + 1] = (f16)Wh[(size_t)(2 * p + 1) * N4U + t];
    }
    wl[g * 1024 + t] = w;
  }

  float creg = 0.0f, hreg = 0.0f;
  if (t < NU) {
    if (t0 != 0) {
      hreg = state[(size_t)b * 2 * NU + t];
      creg = state[(size_t)b * 2 * NU + NU + t];
    }
    hbuf[t] = (f16)hreg;
  }
  __syncthreads();

  float xf = XZ[((size_t)b * tc) * N4U + t];

  for (int s = 0; s < tc; ++s) {
    float a0 = xf + bj;
    float e0 = 0.0f;                  // second accumulator chain (ILP)
    if (s + 1 < tc) {                 // prefetch next step's xz
      xf = XZ[((size_t)b * tc + s + 1) * N4U + t];
    }

    const f16x8* hb8 = (const f16x8*)hbuf;   // broadcast b128 reads of h
#pragma unroll
    for (int g = 0; g < WREG / 4; ++g) {     // pairs 0..91 from VGPRs
      union { f16x8 v; f16x2 p[4]; } u;
      u.v = hb8[g];
#pragma unroll
      for (int q = 0; q < 4; ++q) {
        if (g & 1) e0 = dot2(u.p[q], wr[4 * g + q], e0);
        else       a0 = dot2(u.p[q], wr[4 * g + q], a0);
      }
    }
#pragma unroll
    for (int g = 0; g < WLG; ++g) {          // pairs 92..127 from LDS
      union { f16x8 v; f16x2 p[4]; } u;
      union { f16x8 v; f16x2 p[4]; } w;
      u.v = hb8[WREG / 4 + g];
      w.v = wl[g * 1024 + t];
#pragma unroll
      for (int q = 0; q < 4; ++q) {
        if (g & 1) e0 = dot2(u.p[q], w.p[q], e0);
        else       a0 = dot2(u.p[q], w.p[q], a0);
      }
    }
    a0 += e0;

    zbuf[t] = a0;
    __syncthreads();

    if (t < NU) {
      float zi = zbuf[t];
      float zf = zbuf[t + 256];
      float zg = zbuf[t + 512];
      float zo = zbuf[t + 768];
      float ig = sigm(zi), fg = sigm(zf), og = sigm(zo), gg = tanh_(zg);
      creg = fg * creg + ig * gg;
      hreg = og * tanh_(creg);
      out[((size_t)b * NT + t0 + s) * NU + t] = hreg;
      hbuf[t] = (f16)hreg;
    }
    __syncthreads();
  }

  if (t < NU) {
    state[(size_t)b * 2 * NU + t] = hreg;
    state[(size_t)b * 2 * NU + NU + t] = creg;
  }
}

extern "C" void kernel_launch(void* const* d_in, const int* in_sizes, int n_in,
                              void* d_out, int out_size, void* d_ws, size_t ws_size,
                              hipStream_t stream) {
  const float* inputs = (const float*)d_in[0];  // [64,2048,128]
  const float* Wx     = (const float*)d_in[1];  // [128,1024]
  const float* Wh     = (const float*)d_in[2];  // [256,1024]
  const float* bias   = (const float*)d_in[3];  // [1024]
  float* out = (float*)d_out;                   // [64,2048,256]

  const size_t state_bytes = (size_t)NB * 2 * NU * sizeof(float);  // 128KB
  float* state = (float*)d_ws;
  float* xzbuf = (float*)((char*)d_ws + state_bytes);

  size_t avail = (ws_size > state_bytes) ? (ws_size - state_bytes) : 0;
  size_t step_bytes = (size_t)NB * N4U * sizeof(float);  // 256KB per timestep
  long tc_l = (long)(avail / step_bytes);
  int tc = (tc_l > NT) ? NT : (int)tc_l;
  tc = (tc / 64) * 64;
  if (tc < 64) tc = 64;

  const int smem = WLG * 1024 * (int)sizeof(f16x8);  // 144KB dynamic LDS
  (void)hipFuncSetAttribute((const void*)lstm_seq,
                            hipFuncAttributeMaxDynamicSharedMemorySize, smem);

  for (int t0 = 0; t0 < NT; t0 += tc) {
    int cur = NT - t0;
    if (cur > tc) cur = tc;
    dim3 g1(cur >> 6, NB, 16);
    xz_gemm<<<g1, 256, 0, stream>>>(inputs, Wx, xzbuf, t0, cur);
    lstm_seq<<<NB, 1024, smem, stream>>>(Wh, bias, xzbuf, out, state, t0, cur);
  }
}